// Round 5
// baseline (235.333 us; speedup 1.0000x reference)
//
#include <hip/hip_runtime.h>

#define NG 128      // graphs
#define NPG 64      // nodes per graph
#define IN 16
#define DM 128      // d_model
#define NOUT 64
#define EPG 4096    // edges per graph (64x64)
#define BN_EPS 1e-5f
#define NBLK 256

// ---------------------------------------------------------------------------
// Grid barrier: all NBLK blocks co-resident (capacity >= 2 blocks/CU by LDS &
// launch_bounds; grid == CU count). Device-scope fences per G16: release
// __threadfence (XCD-L2 writeback) + agent atomic; acquire side inv.
// Each barrier has its own counter (memset-zeroed before launch) -> no reuse.
// ---------------------------------------------------------------------------
__device__ __forceinline__ void gbar(unsigned* bar, int idx) {
    __syncthreads();
    if (threadIdx.x == 0) {
        __threadfence();
        __hip_atomic_fetch_add(&bar[idx], 1u, __ATOMIC_ACQ_REL, __HIP_MEMORY_SCOPE_AGENT);
        while (__hip_atomic_load(&bar[idx], __ATOMIC_ACQUIRE, __HIP_MEMORY_SCOPE_AGENT) < (unsigned)NBLK) {
            __builtin_amdgcn_s_sleep(2);
        }
        __threadfence();
    }
    __syncthreads();
}

// One MLP layer (prev-layer BN folded at load). 256 blocks = 128 f-cols x 2
// graph-halves; each (g,f) output computed wholly in-block; stats via atomics.
__device__ __forceinline__ void mlp_stage(
    float* u, const float* __restrict__ vin, const float* __restrict__ statsin,
    const float* __restrict__ gbn, const float* __restrict__ bbn,
    const float* __restrict__ W, const float* __restrict__ bias,
    float* __restrict__ vout, float* __restrict__ statsout)
{
    float* scale_s = u;            // 128
    float* shift_s = u + 128;      // 128
    float* wcol    = u + 256;      // 128
    float* pc      = u + 384;      // 256
    float* h_s     = u + 640;      // 64*129 = 8256
    const int b = blockIdx.x, t = threadIdx.x;
    const int f = b & 127, gh = b >> 7;
    if (t < 128) {
        float s1 = statsin[t * 2], s2 = statsin[t * 2 + 1];
        float m = s1 * (1.f / 128.f);
        float var = s2 * (1.f / 128.f) - m * m;
        float sc = gbn[t] * rsqrtf(var + BN_EPS);
        scale_s[t] = sc;
        shift_s[t] = bbn[t] - m * sc;
        wcol[t] = W[t * 128 + f];
    }
    __syncthreads();
    const int g0r = gh * 64;
    const float4* vin4 = (const float4*)(vin + g0r * 128);
    #pragma unroll
    for (int it = 0; it < 8; ++it) {
        int idx = it * 256 + t;            // 2048 float4 = 64 rows x 128
        int gl = idx >> 5, k4 = (idx & 31) * 4;
        float4 vv = vin4[idx];
        float* hp = h_s + gl * 129 + k4;
        hp[0] = vv.x * scale_s[k4 + 0] + shift_s[k4 + 0];
        hp[1] = vv.y * scale_s[k4 + 1] + shift_s[k4 + 1];
        hp[2] = vv.z * scale_s[k4 + 2] + shift_s[k4 + 2];
        hp[3] = vv.w * scale_s[k4 + 3] + shift_s[k4 + 3];
    }
    __syncthreads();
    {
        const int gl = t & 63, kh = t >> 6;
        float acc = 0.f;
        #pragma unroll 8
        for (int k = kh * 32; k < kh * 32 + 32; ++k) acc += h_s[gl * 129 + k] * wcol[k];
        pc[gl * 4 + kh] = acc;
    }
    __syncthreads();
    if (t < 64) {   // wave 0
        float v = fmaxf(pc[t * 4] + pc[t * 4 + 1] + pc[t * 4 + 2] + pc[t * 4 + 3]
                        + bias[f], 0.f);
        vout[(size_t)(g0r + t) * 128 + f] = v;
        float s1 = v, s2 = v * v;
        #pragma unroll
        for (int off = 32; off > 0; off >>= 1) {
            s1 += __shfl_down(s1, off, 64);
            s2 += __shfl_down(s2, off, 64);
        }
        if (t == 0) {
            atomicAdd(&statsout[f * 2], s1);
            atomicAdd(&statsout[f * 2 + 1], s2);
        }
    }
}

// ---------------------------------------------------------------------------
// THE kernel: 256 blocks x 256 threads, 5 stages, 4 grid barriers.
// ---------------------------------------------------------------------------
__global__ __launch_bounds__(256, 2) void k_all(
    const float* __restrict__ x, const float* __restrict__ ew,
    const float* __restrict__ W1, const float* __restrict__ b1,
    const float* __restrict__ W2, const float* __restrict__ b2,
    const float* __restrict__ Wm0, const float* __restrict__ bm0,
    const float* __restrict__ g0bn, const float* __restrict__ be0,
    const float* __restrict__ Wm1, const float* __restrict__ bm1,
    const float* __restrict__ g1bn, const float* __restrict__ be1,
    const float* __restrict__ Wm2, const float* __restrict__ bm2,
    const float* __restrict__ g2bn, const float* __restrict__ be2,
    const float* __restrict__ Wo, const float* __restrict__ bo,
    float* __restrict__ z, float* __restrict__ part,
    float* __restrict__ v0, float* __restrict__ v1, float* __restrict__ v2,
    float* __restrict__ stats, unsigned* __restrict__ bar,
    float* __restrict__ out)
{
    __shared__ __align__(16) float u[19968];   // ~78KB union (max = stage 1)
    const int b = blockIdx.x, t = threadIdx.x;

    // ================= stage 0a: conv1 -> z (block = graph x f-half) =======
    {
        float* ew_s   = u;            // 4096
        float* x_s    = u + 4096;     // 1024
        float* W1h_s  = u + 5120;     // 1024
        float* P_s    = u + 6144;     // 4096
        float* b1h_s  = u + 10240;    // 64
        float* dinv_s = u + 10304;    // 64
        float* t_s    = u + 10368;    // 64
        const int g = b >> 1, half = b & 1, fh0 = half * 64;
        {
            const float4* ew4 = (const float4*)(ew + g * EPG);
            float4* ews4 = (float4*)ew_s;
            #pragma unroll
            for (int i = 0; i < 4; i++) ews4[t + 256 * i] = ew4[t + 256 * i];
            ((float4*)x_s)[t] = ((const float4*)(x + g * NPG * IN))[t];
        }
        for (int i = t; i < IN * 64; i += 256)
            W1h_s[i] = W1[(i >> 6) * DM + fh0 + (i & 63)];
        if (t < 64) b1h_s[t] = b1[fh0 + t];
        __syncthreads();

        if (t < NPG) {
            float s = 0.f;
            #pragma unroll 8
            for (int i = 0; i < NPG; i++) s += ew_s[i * NPG + t];
            dinv_s[t] = (s > 0.f) ? rsqrtf(s) : 0.f;
        }
        __syncthreads();

        {
            const int j = t & 63, q = t >> 6;
            const float dj = dinv_s[j];
            for (int i = q * 16; i < q * 16 + 16; i++) {
                float vv = ew_s[i * NPG + j] * dj;
                #pragma unroll
                for (int off = 32; off > 0; off >>= 1) vv += __shfl_down(vv, off, 64);
                if (j == 0) t_s[i] = dinv_s[i] * vv * (1.f / 64.f);
            }
        }
        {
            const int f = t & 63, ih = t >> 6;
            for (int i = ih * 16; i < ih * 16 + 16; i++) {
                float acc = 0.f;
                #pragma unroll
                for (int k = 0; k < IN; k++) acc += x_s[i * IN + k] * W1h_s[k * 64 + f];
                P_s[i * 64 + f] = acc;
            }
        }
        __syncthreads();

        for (int i = t; i < EPG; i += 256) ew_s[i] *= dinv_s[i >> 6];
        __syncthreads();

        {
            const int j = t & 63, q = t >> 6, fb = q * 16;
            float acc[16];
            #pragma unroll
            for (int uu = 0; uu < 16; uu++) acc[uu] = 0.f;
            for (int i = 0; i < NPG; i++) {
                const float w = ew_s[i * NPG + j];
                const float4* p4 = (const float4*)(P_s + i * 64 + fb);
                #pragma unroll
                for (int u4 = 0; u4 < 4; u4++) {
                    float4 p = p4[u4];
                    acc[4 * u4 + 0] += w * p.x;
                    acc[4 * u4 + 1] += w * p.y;
                    acc[4 * u4 + 2] += w * p.z;
                    acc[4 * u4 + 3] += w * p.w;
                }
            }
            const float dj = dinv_s[j], tj = t_s[j];
            #pragma unroll
            for (int uu = 0; uu < 16; uu++) {
                float h = fmaxf(dj * acc[uu] + b1h_s[fb + uu], 0.f);
                float zv = tj * h;
                #pragma unroll
                for (int off = 32; off > 0; off >>= 1) zv += __shfl_down(zv, off, 64);
                if (j == 0) z[g * DM + fh0 + fb + uu] = zv;
            }
        }
        __syncthreads();
    }

    // ================= stage 0b: GEMM chunk (40k x 64f) -> part ============
    {
        const int kc = b >> 1, fh = b & 1;
        const int K0 = kc * 40;           // feat col base (x|ew space, 0..5120)
        float* a_s = u;                   // [k][g] 40*132 = 5280
        float* b_s = u + 5280;            // [k][fl] 40*64 = 2560

        #pragma unroll 4
        for (int it = 0; it < 20; ++it) {
            int idx = it * 256 + t;       // 5120 = 40k x 128g
            int k = idx >> 7, gg = idx & 127;
            int K = K0 + k;
            float val = (K < 1024) ? x[gg * 1024 + K] : ew[gg * 4096 + (K - 1024)];
            a_s[k * 132 + gg] = fmaxf(val, 0.f);     // relu(feat)
        }
        #pragma unroll 4
        for (int idx = t; idx < 2560; idx += 256) {
            int k = idx >> 6, fl = idx & 63;
            b_s[k * 64 + fl] = Wm0[(128 + K0 + k) * 128 + fh * 64 + fl];
        }
        __syncthreads();

        const int gthr = t & 31, fthr = t >> 5;
        const int g0 = gthr * 4, f0 = fthr * 8;
        float acc[4][8];
        #pragma unroll
        for (int i = 0; i < 4; i++)
            #pragma unroll
            for (int jx = 0; jx < 8; jx++) acc[i][jx] = 0.f;

        #pragma unroll 4
        for (int k = 0; k < 40; k++) {
            const float4 a4  = *(const float4*)(a_s + k * 132 + g0);
            const float4 c0v = *(const float4*)(b_s + k * 64 + f0);
            const float4 c1v = *(const float4*)(b_s + k * 64 + f0 + 4);
            const float av[4] = {a4.x, a4.y, a4.z, a4.w};
            const float bv[8] = {c0v.x, c0v.y, c0v.z, c0v.w, c1v.x, c1v.y, c1v.z, c1v.w};
            #pragma unroll
            for (int i = 0; i < 4; i++)
                #pragma unroll
                for (int jx = 0; jx < 8; jx++) acc[i][jx] += av[i] * bv[jx];
        }
        float* pp = part + (size_t)b * 8192;   // chunk id == b == kc*2+fh
        #pragma unroll
        for (int i = 0; i < 4; i++) {
            float4* o = (float4*)(pp + (g0 + i) * 64 + f0);
            o[0] = make_float4(acc[i][0], acc[i][1], acc[i][2], acc[i][3]);
            o[1] = make_float4(acc[i][4], acc[i][5], acc[i][6], acc[i][7]);
        }
    }
    gbar(bar, 0);

    // ================= stage 1: reduce + pooled + BN0-relu -> v0, stats0 ===
    {
        float* W2_s     = u;            // 16384
        float* z_s      = u + 16384;    // 512
        float* Wm0s     = u + 16896;    // 2048
        float* pooled_s = u + 18944;    // 520
        float* pps      = u + 19464;    // 64
        float* r1       = u + 19528;    // 256
        float* sv       = u + 19784;    // 64
        float* sv2      = u + 19848;    // 64
        const int fgrp = b & 7, gt = b >> 3;
        const int fsub = t & 15, gl = (t >> 4) & 3, ch = t >> 6;
        const int f = fgrp * 16 + fsub, g = gt * 4 + gl;
        const int fh = f >> 6, fl = f & 63;

        // partial over this thread's 32 k-chunks
        const float* p = part + (size_t)(2 * (ch * 32) + fh) * 8192 + g * 64 + fl;
        float v = 0.f;
        #pragma unroll 8
        for (int cc = 0; cc < 32; cc++) v += p[(size_t)cc * 16384];

        {
            const float4* w24 = (const float4*)W2;
            float4* w2s4 = (float4*)W2_s;
            #pragma unroll
            for (int i = 0; i < 16; i++) w2s4[t + 256 * i] = w24[t + 256 * i];
            if (t < 128) ((float4*)z_s)[t] = ((const float4*)(z + gt * 512))[t];
            for (int idx = t; idx < 2048; idx += 256) {
                int k = idx >> 4, fs = idx & 15;
                Wm0s[idx] = Wm0[k * DM + fgrp * 16 + fs];
            }
        }
        r1[t] = v;
        __syncthreads();

        {   // pooled rows for 4 graphs
            const int gp = t >> 6, k0 = t & 63;
            float a0 = 0.f, a1 = 0.f;
            #pragma unroll 4
            for (int m = 0; m < DM; m++) {
                const float zm = z_s[gp * DM + m];
                a0 += zm * W2_s[m * DM + k0];
                a1 += zm * W2_s[m * DM + k0 + 64];
            }
            pooled_s[gp * 130 + k0]      = fmaxf(a0 + b2[k0], 0.f);
            pooled_s[gp * 130 + k0 + 64] = fmaxf(a1 + b2[k0 + 64], 0.f);
        }
        __syncthreads();
        if (t < 64) {
            const int gl2 = t >> 4, fs = t & 15;
            float a = 0.f;
            #pragma unroll 8
            for (int k = 0; k < DM; k++) a += pooled_s[gl2 * 130 + k] * Wm0s[k * 16 + fs];
            pps[t] = a;
        }
        __syncthreads();
        if (ch == 0) {
            v = r1[t] + r1[t + 64] + r1[t + 128] + r1[t + 192] + bm0[f] + pps[t];
            v = fmaxf(v, 0.f);
            v0[g * DM + f] = v;
            sv[t] = v; sv2[t] = v * v;
        }
        __syncthreads();
        if (t < 16) {
            float s1 = sv[t] + sv[t + 16] + sv[t + 32] + sv[t + 48];
            float s2 = sv2[t] + sv2[t + 16] + sv2[t + 32] + sv2[t + 48];
            atomicAdd(&stats[(fgrp * 16 + t) * 2], s1);
            atomicAdd(&stats[(fgrp * 16 + t) * 2 + 1], s2);
        }
    }
    gbar(bar, 1);

    // ================= stage 2/3: MLP layers =================
    mlp_stage(u, v0, stats,       g0bn, be0, Wm1, bm1, v1, stats + 256);
    gbar(bar, 2);
    mlp_stage(u, v1, stats + 256, g1bn, be1, Wm2, bm2, v2, stats + 512);
    gbar(bar, 3);

    // ================= stage 4: output (block = graph, b < 128) ============
    if (b < 128) {
        float* scale_s = u;            // 128
        float* shift_s = u + 128;      // 128
        float* Wo_s    = u + 256;      // 8192
        float* vrow    = u + 8448;     // 128
        const int g = b;
        const float* statsin = stats + 512;
        if (t < 128) {
            float s1 = statsin[t * 2], s2 = statsin[t * 2 + 1];
            float m = s1 * (1.f / 128.f);
            float var = s2 * (1.f / 128.f) - m * m;
            float sc = g2bn[t] * rsqrtf(var + BN_EPS);
            scale_s[t] = sc;
            shift_s[t] = be2[t] - m * sc;
        }
        __syncthreads();
        {
            const float4* wo4 = (const float4*)Wo;
            float4* wos4 = (float4*)Wo_s;
            #pragma unroll
            for (int it = 0; it < 8; it++) wos4[it * 256 + t] = wo4[it * 256 + t];
        }
        if (t < 32) {
            float4 vv = ((const float4*)(v2 + g * 128))[t];
            int k4 = t * 4;
            vrow[k4 + 0] = vv.x * scale_s[k4 + 0] + shift_s[k4 + 0];
            vrow[k4 + 1] = vv.y * scale_s[k4 + 1] + shift_s[k4 + 1];
            vrow[k4 + 2] = vv.z * scale_s[k4 + 2] + shift_s[k4 + 2];
            vrow[k4 + 3] = vv.w * scale_s[k4 + 3] + shift_s[k4 + 3];
        }
        __syncthreads();
        if (t < 64) {
            float acc = bo[t];
            #pragma unroll 8
            for (int k = 0; k < 128; k++) acc += vrow[k] * Wo_s[k * 64 + t];
            out[g * NOUT + t] = acc;
        }
    }
}

extern "C" void kernel_launch(void* const* d_in, const int* in_sizes, int n_in,
                              void* d_out, int out_size, void* d_ws, size_t ws_size,
                              hipStream_t stream)
{
    const float* x   = (const float*)d_in[0];
    const float* ew  = (const float*)d_in[2];
    const float* W1  = (const float*)d_in[4];
    const float* b1  = (const float*)d_in[5];
    const float* W2  = (const float*)d_in[6];
    const float* b2  = (const float*)d_in[7];
    const float* Wm0 = (const float*)d_in[8];
    const float* bm0 = (const float*)d_in[9];
    const float* g0  = (const float*)d_in[10];
    const float* be0 = (const float*)d_in[11];
    const float* Wm1 = (const float*)d_in[12];
    const float* bm1 = (const float*)d_in[13];
    const float* g1  = (const float*)d_in[14];
    const float* be1 = (const float*)d_in[15];
    const float* Wm2 = (const float*)d_in[16];
    const float* bm2 = (const float*)d_in[17];
    const float* g2  = (const float*)d_in[18];
    const float* be2 = (const float*)d_in[19];
    const float* Wo  = (const float*)d_in[20];
    const float* bo  = (const float*)d_in[21];

    float* ws    = (float*)d_ws;
    float* zbuf  = ws;                        // 16384
    float* part  = zbuf + 16384;              // 256*8192 = 2097152
    float* v0    = part + 256 * 8192;         // 16384
    float* v1    = v0 + 16384;                // 16384
    float* v2    = v1 + 16384;                // 16384
    float* stats = v2 + 16384;                // 768 (stats0|stats1|stats2)
    unsigned* bar = (unsigned*)(stats + 768); // 8 counters

    // zero stats + barrier counters (graph-capture-legal async memset)
    hipMemsetAsync(stats, 0, (768 + 8) * sizeof(float), stream);

    k_all<<<NBLK, 256, 0, stream>>>(
        x, ew, W1, b1, W2, b2, Wm0, bm0, g0, be0,
        Wm1, bm1, g1, be1, Wm2, bm2, g2, be2, Wo, bo,
        zbuf, part, v0, v1, v2, stats, bar, (float*)d_out);
}

// Round 6
// 136.936 us; speedup vs baseline: 1.7186x; 1.7186x over previous
//
#include <hip/hip_runtime.h>

#define NG 128      // graphs
#define NPG 64      // nodes per graph
#define IN 16
#define DM 128      // d_model
#define NOUT 64
#define EPG 4096    // edges per graph (64x64)
#define NGEMM 160   // x/ew chunks: 80 k-chunks(64) x 2 f-halves(64)
#define BN_EPS 1e-5f

// ---------------------------------------------------------------------------
// K_A "front": blocks 0..127 = conv1 per graph (full f=128) -> z;
//              blocks 128..287 = big-GEMM x/ew chunks (64k x 64f) -> part.
// Block 0 also zeroes the 768-float stats region.
// Conv path uses register-blocked tiles (4x8 acc per thread) for both
// P = x@W1 (64x128x16) and the aggregation (64x128x64) -> ~4x fewer ds ops.
// ---------------------------------------------------------------------------
__global__ __launch_bounds__(256) void k_front(
    const float* __restrict__ x, const float* __restrict__ ew,
    const float* __restrict__ W1, const float* __restrict__ b1,
    const float* __restrict__ Wm0,
    float* __restrict__ z, float* __restrict__ part, float* __restrict__ stats)
{
    __shared__ __align__(16) float u[15616];   // 61KB union
    const int b = blockIdx.x, t = threadIdx.x;

    if (b < 128) {
        // ---------------- conv path (one block per graph) ----------------
        float* ew_s   = u;             // [i][j] 4096, later scaled by dinv_i
        float* x_s    = u + 4096;      // x^T [k][i] 1024
        float* W1_s   = u + 5120;      // [k][f] 2048
        float* P_s    = u + 7168;      // [i][f] 8192
        float* b1_s   = u + 15360;     // 128
        float* dinv_s = u + 15488;     // 64
        float* t_s    = u + 15552;     // 64
        float* zp     = u + 4096;      // overlay (x_s/W1_s dead after P): 16*132
        const int g = b;
        if (b == 0) {
            for (int i = t; i < 768; i += 256) stats[i] = 0.f;
        }
        // stage: ew (vectorized), x transposed, W1 direct, b1
        {
            const float4* ew4 = (const float4*)(ew + g * EPG);
            float4* ews4 = (float4*)ew_s;
            #pragma unroll
            for (int i = 0; i < 4; i++) ews4[t + 256 * i] = ew4[t + 256 * i];
            // x^T: thread (i = t&63, k4 = (t>>6)*4)
            const int xi = t & 63, k4 = (t >> 6) * 4;
            float4 xv = *(const float4*)(x + g * NPG * IN + xi * IN + k4);
            x_s[(k4 + 0) * 64 + xi] = xv.x;
            x_s[(k4 + 1) * 64 + xi] = xv.y;
            x_s[(k4 + 2) * 64 + xi] = xv.z;
            x_s[(k4 + 3) * 64 + xi] = xv.w;
            ((float4*)W1_s)[t]       = ((const float4*)W1)[t];
            ((float4*)W1_s)[t + 256] = ((const float4*)W1)[t + 256];
            if (t < 128) b1_s[t] = b1[t];
        }
        __syncthreads();

        // dinv: column sums of unscaled ew (lanes consecutive: conflict-free)
        if (t < NPG) {
            float s = 0.f;
            #pragma unroll 8
            for (int i = 0; i < NPG; i++) s += ew_s[i * NPG + t];
            dinv_s[t] = (s > 0.f) ? rsqrtf(s) : 0.f;
        }
        __syncthreads();

        // t_s[i] = dinv_i * (sum_j ew[i,j] dinv_j) / 64  (per-wave row reduce)
        {
            const int j = t & 63, q = t >> 6;
            const float dj = dinv_s[j];
            for (int i = q * 16; i < q * 16 + 16; i++) {
                float vv = ew_s[i * NPG + j] * dj;
                #pragma unroll
                for (int off = 32; off > 0; off >>= 1) vv += __shfl_down(vv, off, 64);
                if (j == 0) t_s[i] = dinv_s[i] * vv * (1.f / 64.f);
            }
        }
        __syncthreads();

        // P = x @ W1 (64x128x16), register-blocked: thread (it = t&15, ft = t>>4)
        {
            const int it = t & 15, ft = t >> 4;
            const int i0 = it * 4, f0 = ft * 8;
            float accp[4][8];
            #pragma unroll
            for (int a = 0; a < 4; a++)
                #pragma unroll
                for (int c = 0; c < 8; c++) accp[a][c] = 0.f;
            #pragma unroll
            for (int k = 0; k < IN; k++) {
                const float4 a4  = *(const float4*)(x_s + k * 64 + i0);
                const float4 b0v = *(const float4*)(W1_s + k * DM + f0);
                const float4 b1v = *(const float4*)(W1_s + k * DM + f0 + 4);
                const float av[4] = {a4.x, a4.y, a4.z, a4.w};
                const float bv[8] = {b0v.x, b0v.y, b0v.z, b0v.w, b1v.x, b1v.y, b1v.z, b1v.w};
                #pragma unroll
                for (int a = 0; a < 4; a++)
                    #pragma unroll
                    for (int c = 0; c < 8; c++) accp[a][c] += av[a] * bv[c];
            }
            #pragma unroll
            for (int a = 0; a < 4; a++) {
                float4* o = (float4*)(P_s + (i0 + a) * DM + f0);
                o[0] = make_float4(accp[a][0], accp[a][1], accp[a][2], accp[a][3]);
                o[1] = make_float4(accp[a][4], accp[a][5], accp[a][6], accp[a][7]);
            }
        }
        __syncthreads();

        // scale rows in place: ew_s[i][j] = dinv_i * ew[i][j]
        for (int i = t; i < EPG; i += 256) ew_s[i] *= dinv_s[i >> 6];
        __syncthreads();

        // aggregation: out[j,f] = sum_k ew'[k,j] * P[k,f]  (64x128x64)
        // thread (jt = t&15, ft = t>>4): acc[4j][8f]
        {
            const int jt = t & 15, ft = t >> 4;
            const int j0 = jt * 4, f0 = ft * 8;
            float acc[4][8];
            #pragma unroll
            for (int a = 0; a < 4; a++)
                #pragma unroll
                for (int c = 0; c < 8; c++) acc[a][c] = 0.f;
            #pragma unroll 4
            for (int k = 0; k < 64; k++) {
                const float4 a4  = *(const float4*)(ew_s + k * 64 + j0);
                const float4 b0v = *(const float4*)(P_s + k * DM + f0);
                const float4 b1v = *(const float4*)(P_s + k * DM + f0 + 4);
                const float av[4] = {a4.x, a4.y, a4.z, a4.w};
                const float bv[8] = {b0v.x, b0v.y, b0v.z, b0v.w, b1v.x, b1v.y, b1v.z, b1v.w};
                #pragma unroll
                for (int a = 0; a < 4; a++)
                    #pragma unroll
                    for (int c = 0; c < 8; c++) acc[a][c] += av[a] * bv[c];
            }
            // h = relu(dinv_j*acc + b1);  z-partials over this thread's 4 j's
            float zpart[8];
            #pragma unroll
            for (int c = 0; c < 8; c++) zpart[c] = 0.f;
            #pragma unroll
            for (int a = 0; a < 4; a++) {
                const float dj = dinv_s[j0 + a], tj = t_s[j0 + a];
                #pragma unroll
                for (int c = 0; c < 8; c++) {
                    float h = fmaxf(dj * acc[a][c] + b1_s[f0 + c], 0.f);
                    zpart[c] += tj * h;
                }
            }
            float4* zo = (float4*)(zp + jt * 132 + f0);
            zo[0] = make_float4(zpart[0], zpart[1], zpart[2], zpart[3]);
            zo[1] = make_float4(zpart[4], zpart[5], zpart[6], zpart[7]);
        }
        __syncthreads();

        // final z reduce over 16 jt
        if (t < 128) {
            float s = 0.f;
            #pragma unroll
            for (int jt = 0; jt < 16; jt++) s += zp[jt * 132 + t];
            z[g * DM + t] = s;
        }
    } else {
        // ---------------- gemm x/ew chunk path (unchanged R4) ----------------
        const int c = b - 128;
        const int kc = c >> 1, fh = c & 1;
        float* a_s = u;             // [k][g] 64*132 = 8448
        float* b_s = u + 8448;      // [k][fl] 64*64 = 4096

        const float* src; int stride, off;
        if (kc < 16) { src = x;  stride = 1024; off = kc * 64; }
        else         { src = ew; stride = 4096; off = (kc - 16) * 64; }
        const int K0 = 128 + kc * 64;

        #pragma unroll 4
        for (int it = 0; it < 32; it++) {
            int idx = it * 256 + t;
            int gg = idx >> 6, k = idx & 63;
            a_s[k * 132 + gg] = fmaxf(src[gg * stride + off + k], 0.f);
        }
        #pragma unroll 4
        for (int it = 0; it < 16; it++) {
            int idx = it * 256 + t;
            int k = idx >> 6, fl = idx & 63;
            b_s[k * 64 + fl] = Wm0[(K0 + k) * 128 + fh * 64 + fl];
        }
        __syncthreads();

        const int gthr = t & 31, fthr = t >> 5;   // 32 x 8
        const int g0 = gthr * 4, f0 = fthr * 8;
        float acc[4][8];
        #pragma unroll
        for (int i = 0; i < 4; i++)
            #pragma unroll
            for (int jx = 0; jx < 8; jx++) acc[i][jx] = 0.f;

        #pragma unroll 4
        for (int k = 0; k < 64; k++) {
            const float4 a4  = *(const float4*)(a_s + k * 132 + g0);
            const float4 c0v = *(const float4*)(b_s + k * 64 + f0);
            const float4 c1v = *(const float4*)(b_s + k * 64 + f0 + 4);
            const float av[4] = {a4.x, a4.y, a4.z, a4.w};
            const float bv[8] = {c0v.x, c0v.y, c0v.z, c0v.w, c1v.x, c1v.y, c1v.z, c1v.w};
            #pragma unroll
            for (int i = 0; i < 4; i++)
                #pragma unroll
                for (int jx = 0; jx < 8; jx++) acc[i][jx] += av[i] * bv[jx];
        }

        float* pp = part + c * 8192;    // [g][fl] 128x64
        #pragma unroll
        for (int i = 0; i < 4; i++) {
            float4* o = (float4*)(pp + (g0 + i) * 64 + f0);
            o[0] = make_float4(acc[i][0], acc[i][1], acc[i][2], acc[i][3]);
            o[1] = make_float4(acc[i][4], acc[i][5], acc[i][6], acc[i][7]);
        }
    }
}

// ---------------------------------------------------------------------------
// K_B: reduce 160 partials + (in-block) pooled contribution + bm0 + relu -> v0;
// BN0 stats atomics. 256 blocks = 32 g-tiles x 8 f-grps.  (unchanged R4)
// ---------------------------------------------------------------------------
__global__ __launch_bounds__(256) void k_reduce_bn0(
    const float* __restrict__ part, const float* __restrict__ zbuf,
    const float* __restrict__ W2, const float* __restrict__ b2,
    const float* __restrict__ Wm0, const float* __restrict__ bm0,
    float* __restrict__ v0, float* __restrict__ stats0)
{
    __shared__ __align__(16) float W2_s[16384];     // 64KB [m][k]
    __shared__ __align__(16) float z_s[512];        // 4 graph rows
    __shared__ float Wm0s[2048];                    // [k][fsub] 8KB
    __shared__ float pooled_s[4 * 130];
    __shared__ float pps[64];
    __shared__ float r1[256];
    __shared__ float sv[64], sv2[64];

    const int bx = blockIdx.x, t = threadIdx.x;
    const int fgrp = bx & 7, gt = bx >> 3;
    const int fsub = t & 15, gl = (t >> 4) & 3, ch = t >> 6;
    const int f = fgrp * 16 + fsub, g = gt * 4 + gl;
    const int fh = f >> 6, fl = f & 63;

    const float* p = part + (size_t)(2 * (ch * 20) + fh) * 8192 + g * 64 + fl;
    float v = 0.f;
    #pragma unroll 5
    for (int cc = 0; cc < 20; cc++) v += p[(size_t)cc * 2 * 8192];

    {
        const float4* w24 = (const float4*)W2;
        float4* w2s4 = (float4*)W2_s;
        #pragma unroll
        for (int i = 0; i < 16; i++) w2s4[t + 256 * i] = w24[t + 256 * i];
        if (t < 128) ((float4*)z_s)[t] = ((const float4*)(zbuf + gt * 512))[t];
        for (int idx = t; idx < 2048; idx += 256) {
            int k = idx >> 4, fs = idx & 15;
            Wm0s[idx] = Wm0[k * DM + fgrp * 16 + fs];
        }
    }
    r1[t] = v;
    __syncthreads();

    {   // pooled rows for 4 graphs
        const int gp = t >> 6, k0 = t & 63;
        float a0 = 0.f, a1 = 0.f;
        #pragma unroll 4
        for (int m = 0; m < DM; m++) {
            const float zm = z_s[gp * DM + m];
            a0 += zm * W2_s[m * DM + k0];
            a1 += zm * W2_s[m * DM + k0 + 64];
        }
        pooled_s[gp * 130 + k0]      = fmaxf(a0 + b2[k0], 0.f);
        pooled_s[gp * 130 + k0 + 64] = fmaxf(a1 + b2[k0 + 64], 0.f);
    }
    __syncthreads();
    if (t < 64) {
        const int gl2 = t >> 4, fs = t & 15;
        float a = 0.f;
        #pragma unroll 8
        for (int k = 0; k < DM; k++) a += pooled_s[gl2 * 130 + k] * Wm0s[k * 16 + fs];
        pps[t] = a;
    }
    __syncthreads();
    if (ch == 0) {
        v = r1[t] + r1[t + 64] + r1[t + 128] + r1[t + 192] + bm0[f] + pps[t];
        v = fmaxf(v, 0.f);
        v0[g * DM + f] = v;
        sv[t] = v; sv2[t] = v * v;
    }
    __syncthreads();
    if (t < 16) {
        float s1 = sv[t] + sv[t + 16] + sv[t + 32] + sv[t + 48];
        float s2 = sv2[t] + sv2[t + 16] + sv2[t + 32] + sv2[t + 48];
        atomicAdd(&stats0[(fgrp * 16 + t) * 2], s1);
        atomicAdd(&stats0[(fgrp * 16 + t) * 2 + 1], s2);
    }
}

// ---------------------------------------------------------------------------
// K5/K6: one MLP layer (unchanged R4).
// ---------------------------------------------------------------------------
__global__ __launch_bounds__(256) void k_mlp(
    const float* __restrict__ vin, const float* __restrict__ statsin,
    const float* __restrict__ gbn, const float* __restrict__ bbn,
    const float* __restrict__ W, const float* __restrict__ bias,
    float* __restrict__ vout, float* __restrict__ statsout)
{
    __shared__ float h_s[128 * 129];
    __shared__ float wcol[128];
    __shared__ float scale_s[128], shift_s[128];
    __shared__ float pc[128];
    __shared__ float rr[4];
    const int f = blockIdx.x, t = threadIdx.x;
    if (t < 128) {
        float s1 = statsin[t * 2], s2 = statsin[t * 2 + 1];
        float m = s1 * (1.f / 128.f);
        float var = s2 * (1.f / 128.f) - m * m;
        float sc = gbn[t] * rsqrtf(var + BN_EPS);
        scale_s[t] = sc;
        shift_s[t] = bbn[t] - m * sc;
        wcol[t] = W[t * 128 + f];
    }
    __syncthreads();
    #pragma unroll 4
    for (int it = 0; it < 16; it++) {
        int idx = it * 256 + t;           // float4 index (4096 total)
        int g = idx >> 5, k4 = (idx & 31) * 4;
        float4 vv = ((const float4*)vin)[idx];
        float* hp = h_s + g * 129 + k4;
        hp[0] = vv.x * scale_s[k4 + 0] + shift_s[k4 + 0];
        hp[1] = vv.y * scale_s[k4 + 1] + shift_s[k4 + 1];
        hp[2] = vv.z * scale_s[k4 + 2] + shift_s[k4 + 2];
        hp[3] = vv.w * scale_s[k4 + 3] + shift_s[k4 + 3];
    }
    __syncthreads();
    const int g = t & 127, kh = t >> 7;
    float acc = 0.f;
    #pragma unroll 8
    for (int k = kh * 64; k < kh * 64 + 64; k++) acc += h_s[g * 129 + k] * wcol[k];
    if (kh) pc[g] = acc;
    __syncthreads();
    if (t < 128) {
        float v = fmaxf(acc + pc[t] + bias[f], 0.f);
        vout[t * 128 + f] = v;
        float s1 = v, s2 = v * v;
        #pragma unroll
        for (int off = 32; off > 0; off >>= 1) {
            s1 += __shfl_down(s1, off, 64);
            s2 += __shfl_down(s2, off, 64);
        }
        if ((t & 63) == 0) { rr[(t >> 6) * 2] = s1; rr[(t >> 6) * 2 + 1] = s2; }
    }
    __syncthreads();
    if (t == 0) {
        statsout[f * 2]     = rr[0] + rr[2];
        statsout[f * 2 + 1] = rr[1] + rr[3];
    }
}

// ---------------------------------------------------------------------------
// K7: output layer (unchanged R4).
// ---------------------------------------------------------------------------
__global__ __launch_bounds__(128) void k_out(
    const float* __restrict__ vin, const float* __restrict__ statsin,
    const float* __restrict__ gbn, const float* __restrict__ bbn,
    const float* __restrict__ Wo, const float* __restrict__ bo,
    float* __restrict__ out)
{
    __shared__ __align__(16) float Wo_s[128 * 64];   // 32KB
    __shared__ float vrow[2][128];
    __shared__ float scale_s[128], shift_s[128];
    const int b = blockIdx.x, t = threadIdx.x, g0 = b * 2;
    {
        float s1 = statsin[t * 2], s2 = statsin[t * 2 + 1];
        float m = s1 * (1.f / 128.f);
        float var = s2 * (1.f / 128.f) - m * m;
        float sc = gbn[t] * rsqrtf(var + BN_EPS);
        scale_s[t] = sc;
        shift_s[t] = bbn[t] - m * sc;
    }
    __syncthreads();
    {
        const float4* wo4 = (const float4*)Wo;
        float4* wos4 = (float4*)Wo_s;
        #pragma unroll
        for (int it = 0; it < 16; it++) wos4[it * 128 + t] = wo4[it * 128 + t];
    }
    if (t < 64) {
        int g2 = t >> 5, k4 = (t & 31) * 4;
        float4 vv = ((const float4*)(vin + g0 * 128))[t];
        vrow[g2][k4 + 0] = vv.x * scale_s[k4 + 0] + shift_s[k4 + 0];
        vrow[g2][k4 + 1] = vv.y * scale_s[k4 + 1] + shift_s[k4 + 1];
        vrow[g2][k4 + 2] = vv.z * scale_s[k4 + 2] + shift_s[k4 + 2];
        vrow[g2][k4 + 3] = vv.w * scale_s[k4 + 3] + shift_s[k4 + 3];
    }
    __syncthreads();
    const int g2 = t >> 6, o = t & 63;
    float acc = bo[o];
    #pragma unroll 8
    for (int k = 0; k < 128; k++) acc += vrow[g2][k] * Wo_s[k * 64 + o];
    out[(g0 + g2) * NOUT + o] = acc;
}

extern "C" void kernel_launch(void* const* d_in, const int* in_sizes, int n_in,
                              void* d_out, int out_size, void* d_ws, size_t ws_size,
                              hipStream_t stream)
{
    const float* x   = (const float*)d_in[0];
    const float* ew  = (const float*)d_in[2];
    const float* W1  = (const float*)d_in[4];
    const float* b1  = (const float*)d_in[5];
    const float* W2  = (const float*)d_in[6];
    const float* b2  = (const float*)d_in[7];
    const float* Wm0 = (const float*)d_in[8];
    const float* bm0 = (const float*)d_in[9];
    const float* g0  = (const float*)d_in[10];
    const float* be0 = (const float*)d_in[11];
    const float* Wm1 = (const float*)d_in[12];
    const float* bm1 = (const float*)d_in[13];
    const float* g1  = (const float*)d_in[14];
    const float* be1 = (const float*)d_in[15];
    const float* Wm2 = (const float*)d_in[16];
    const float* bm2 = (const float*)d_in[17];
    const float* g2  = (const float*)d_in[18];
    const float* be2 = (const float*)d_in[19];
    const float* Wo  = (const float*)d_in[20];
    const float* bo  = (const float*)d_in[21];

    float* ws     = (float*)d_ws;
    float* zbuf   = ws;                       // 16384
    float* part   = zbuf + 16384;             // 160*8192 = 1310720
    float* v0     = part + NGEMM * 8192;      // 16384
    float* v1     = v0 + 16384;               // 16384
    float* v2     = v1 + 16384;               // 16384
    float* stats  = v2 + 16384;               // 768 (stats0|stats1|stats2)

    k_front<<<128 + NGEMM, 256, 0, stream>>>(x, ew, W1, b1, Wm0, zbuf, part, stats);
    k_reduce_bn0<<<256, 256, 0, stream>>>(part, zbuf, W2, b2, Wm0, bm0, v0, stats);
    k_mlp<<<128, 256, 0, stream>>>(v0, stats,       g0, be0, Wm1, bm1, v1, stats + 256);
    k_mlp<<<128, 256, 0, stream>>>(v1, stats + 256, g1, be1, Wm2, bm2, v2, stats + 512);
    k_out<<<NOUT, 128, 0, stream>>>(v2, stats + 512, g2, be2, Wo, bo, (float*)d_out);
}

// Round 7
// 135.987 us; speedup vs baseline: 1.7306x; 1.0070x over previous
//
#include <hip/hip_runtime.h>

#define NG 128      // graphs
#define NPG 64      // nodes per graph
#define IN 16
#define DM 128      // d_model
#define NOUT 64
#define EPG 4096    // edges per graph (64x64)
#define NCH 128     // gemm chunks: 64 k-chunks(80) x 2 f-halves(64)
#define BN_EPS 1e-5f

// ---------------------------------------------------------------------------
// K_A "front": 256 blocks, one per CU.
//   blocks 0..127  = conv1 per graph -> pooled -> ppart (Wm0[0:128] product)
//   blocks 128..255 = big-GEMM x/ew chunks (80k x 64f) -> part
// Block 0 zeroes the 768-float stats region (used by later dispatches only).
// ---------------------------------------------------------------------------
__global__ __launch_bounds__(256) void k_front(
    const float* __restrict__ x, const float* __restrict__ ew,
    const float* __restrict__ W1, const float* __restrict__ b1,
    const float* __restrict__ W2, const float* __restrict__ b2,
    const float* __restrict__ Wm0,
    float* __restrict__ part, float* __restrict__ ppart,
    float* __restrict__ stats)
{
    __shared__ __align__(16) float u[16128];   // 63KB union
    const int bid = blockIdx.x, t = threadIdx.x;

    if (bid < 128) {
        // ---------------- conv path (one block per graph) ----------------
        float* ew_s     = u;             // [i][j] 4096, later scaled by dinv_i
        float* x_s      = u + 4096;      // x^T [k][i] 1024
        float* W1_s     = u + 5120;      // [k][f] 2048
        float* P_s      = u + 7168;      // [i][f] 8192
        float* b1_s     = u + 15360;     // 128
        float* dinv_s   = u + 15488;     // 64
        float* t_s      = u + 15552;     // 64
        float* zp       = u + 4096;      // overlay (x_s/W1_s dead after P): 16*132
        float* z_full   = u + 15616;     // 128
        float* pooled_s = u + 15744;     // 128
        float* pp2      = u + 15872;     // 256
        const int g = bid;
        if (bid == 0) {
            for (int i = t; i < 768; i += 256) stats[i] = 0.f;
        }
        // stage: ew (vectorized), x transposed, W1 direct, b1
        {
            const float4* ew4 = (const float4*)(ew + g * EPG);
            float4* ews4 = (float4*)ew_s;
            #pragma unroll
            for (int i = 0; i < 4; i++) ews4[t + 256 * i] = ew4[t + 256 * i];
            const int xi = t & 63, k4 = (t >> 6) * 4;
            float4 xv = *(const float4*)(x + g * NPG * IN + xi * IN + k4);
            x_s[(k4 + 0) * 64 + xi] = xv.x;
            x_s[(k4 + 1) * 64 + xi] = xv.y;
            x_s[(k4 + 2) * 64 + xi] = xv.z;
            x_s[(k4 + 3) * 64 + xi] = xv.w;
            ((float4*)W1_s)[t]       = ((const float4*)W1)[t];
            ((float4*)W1_s)[t + 256] = ((const float4*)W1)[t + 256];
            if (t < 128) b1_s[t] = b1[t];
        }
        __syncthreads();

        // dinv: column sums of unscaled ew
        if (t < NPG) {
            float s = 0.f;
            #pragma unroll 8
            for (int i = 0; i < NPG; i++) s += ew_s[i * NPG + t];
            dinv_s[t] = (s > 0.f) ? rsqrtf(s) : 0.f;
        }
        __syncthreads();

        // t_s[i] = dinv_i * (sum_j ew[i,j] dinv_j) / 64
        {
            const int j = t & 63, q = t >> 6;
            const float dj = dinv_s[j];
            for (int i = q * 16; i < q * 16 + 16; i++) {
                float vv = ew_s[i * NPG + j] * dj;
                #pragma unroll
                for (int off = 32; off > 0; off >>= 1) vv += __shfl_down(vv, off, 64);
                if (j == 0) t_s[i] = dinv_s[i] * vv * (1.f / 64.f);
            }
        }
        __syncthreads();

        // P = x @ W1 (64x128x16), register-blocked 4x8
        {
            const int it = t & 15, ft = t >> 4;
            const int i0 = it * 4, f0 = ft * 8;
            float accp[4][8];
            #pragma unroll
            for (int a = 0; a < 4; a++)
                #pragma unroll
                for (int c = 0; c < 8; c++) accp[a][c] = 0.f;
            #pragma unroll
            for (int k = 0; k < IN; k++) {
                const float4 a4  = *(const float4*)(x_s + k * 64 + i0);
                const float4 b0v = *(const float4*)(W1_s + k * DM + f0);
                const float4 b1v = *(const float4*)(W1_s + k * DM + f0 + 4);
                const float av[4] = {a4.x, a4.y, a4.z, a4.w};
                const float bv[8] = {b0v.x, b0v.y, b0v.z, b0v.w, b1v.x, b1v.y, b1v.z, b1v.w};
                #pragma unroll
                for (int a = 0; a < 4; a++)
                    #pragma unroll
                    for (int c = 0; c < 8; c++) accp[a][c] += av[a] * bv[c];
            }
            #pragma unroll
            for (int a = 0; a < 4; a++) {
                float4* o = (float4*)(P_s + (i0 + a) * DM + f0);
                o[0] = make_float4(accp[a][0], accp[a][1], accp[a][2], accp[a][3]);
                o[1] = make_float4(accp[a][4], accp[a][5], accp[a][6], accp[a][7]);
            }
        }
        __syncthreads();

        // scale rows in place: ew_s[i][j] = dinv_i * ew[i][j]
        for (int i = t; i < EPG; i += 256) ew_s[i] *= dinv_s[i >> 6];
        __syncthreads();

        // aggregation: h[j,f] = relu(dinv_j * sum_k ew'[k,j] P[k,f] + b1[f]);
        // z-partials per thread -> zp
        {
            const int jt = t & 15, ft = t >> 4;
            const int j0 = jt * 4, f0 = ft * 8;
            float acc[4][8];
            #pragma unroll
            for (int a = 0; a < 4; a++)
                #pragma unroll
                for (int c = 0; c < 8; c++) acc[a][c] = 0.f;
            #pragma unroll 4
            for (int k = 0; k < 64; k++) {
                const float4 a4  = *(const float4*)(ew_s + k * 64 + j0);
                const float4 b0v = *(const float4*)(P_s + k * DM + f0);
                const float4 b1v = *(const float4*)(P_s + k * DM + f0 + 4);
                const float av[4] = {a4.x, a4.y, a4.z, a4.w};
                const float bv[8] = {b0v.x, b0v.y, b0v.z, b0v.w, b1v.x, b1v.y, b1v.z, b1v.w};
                #pragma unroll
                for (int a = 0; a < 4; a++)
                    #pragma unroll
                    for (int c = 0; c < 8; c++) acc[a][c] += av[a] * bv[c];
            }
            float zpart[8];
            #pragma unroll
            for (int c = 0; c < 8; c++) zpart[c] = 0.f;
            #pragma unroll
            for (int a = 0; a < 4; a++) {
                const float dj = dinv_s[j0 + a], tj = t_s[j0 + a];
                #pragma unroll
                for (int c = 0; c < 8; c++) {
                    float h = fmaxf(dj * acc[a][c] + b1_s[f0 + c], 0.f);
                    zpart[c] += tj * h;
                }
            }
            float4* zo = (float4*)(zp + jt * 132 + f0);
            zo[0] = make_float4(zpart[0], zpart[1], zpart[2], zpart[3]);
            zo[1] = make_float4(zpart[4], zpart[5], zpart[6], zpart[7]);
        }
        __syncthreads();

        // z (LDS-resident only)
        if (t < 128) {
            float s = 0.f;
            #pragma unroll
            for (int jt = 0; jt < 16; jt++) s += zp[jt * 132 + t];
            z_full[t] = s;
        }
        __syncthreads();

        // pooled = relu(z @ W2 + b2): thread (c = t&127, kh = t>>7)
        {
            const int c = t & 127, kh = t >> 7;
            float acc = 0.f;
            #pragma unroll 8
            for (int k = kh * 64; k < kh * 64 + 64; k++)
                acc += z_full[k] * W2[k * DM + c];
            pp2[kh * 128 + c] = acc;
        }
        __syncthreads();
        if (t < 128) pooled_s[t] = fmaxf(pp2[t] + pp2[128 + t] + b2[t], 0.f);
        __syncthreads();

        // ppart = pooled @ Wm0[0:128,:]
        {
            const int f = t & 127, kh = t >> 7;
            float acc = 0.f;
            #pragma unroll 8
            for (int k = kh * 64; k < kh * 64 + 64; k++)
                acc += pooled_s[k] * Wm0[k * DM + f];
            pp2[kh * 128 + f] = acc;
        }
        __syncthreads();
        if (t < 128) ppart[g * DM + t] = pp2[t] + pp2[128 + t];
    } else {
        // ---------------- gemm x/ew chunk path (K=80) ----------------
        const int c = bid - 128;
        const int kc = c >> 1, fh = c & 1;
        const int K0 = kc * 80;          // feat col base in x|ew space (0..5120)
        float* a_s = u;                  // [k][g] 80*132 = 10560
        float* b_s = u + 10560;          // [k][fl] 80*64 = 5120

        // a: k in [0,64): coalesced along k per g
        #pragma unroll 4
        for (int it = 0; it < 32; it++) {
            int idx = it * 256 + t;
            int gg = idx >> 6, k = idx & 63;
            int K = K0 + k;
            float val = (K < 1024) ? x[gg * 1024 + K] : ew[gg * 4096 + (K - 1024)];
            a_s[k * 132 + gg] = fmaxf(val, 0.f);
        }
        // a: k in [64,80)
        #pragma unroll 4
        for (int it = 0; it < 8; it++) {
            int idx = it * 256 + t;
            int gg = idx >> 4, k = 64 + (idx & 15);
            int K = K0 + k;
            float val = (K < 1024) ? x[gg * 1024 + K] : ew[gg * 4096 + (K - 1024)];
            a_s[k * 132 + gg] = fmaxf(val, 0.f);
        }
        // b: Wm0 rows 128+K0 .. +80, this f-half
        #pragma unroll 4
        for (int it = 0; it < 20; it++) {
            int idx = it * 256 + t;
            int k = idx >> 6, fl = idx & 63;
            b_s[k * 64 + fl] = Wm0[(128 + K0 + k) * 128 + fh * 64 + fl];
        }
        __syncthreads();

        const int gthr = t & 31, fthr = t >> 5;   // 32 x 8
        const int g0 = gthr * 4, f0 = fthr * 8;
        float acc[4][8];
        #pragma unroll
        for (int i = 0; i < 4; i++)
            #pragma unroll
            for (int jx = 0; jx < 8; jx++) acc[i][jx] = 0.f;

        #pragma unroll 4
        for (int k = 0; k < 80; k++) {
            const float4 a4  = *(const float4*)(a_s + k * 132 + g0);
            const float4 c0v = *(const float4*)(b_s + k * 64 + f0);
            const float4 c1v = *(const float4*)(b_s + k * 64 + f0 + 4);
            const float av[4] = {a4.x, a4.y, a4.z, a4.w};
            const float bv[8] = {c0v.x, c0v.y, c0v.z, c0v.w, c1v.x, c1v.y, c1v.z, c1v.w};
            #pragma unroll
            for (int i = 0; i < 4; i++)
                #pragma unroll
                for (int jx = 0; jx < 8; jx++) acc[i][jx] += av[i] * bv[jx];
        }

        float* pp = part + (size_t)c * 8192;    // [g][fl] 128x64
        #pragma unroll
        for (int i = 0; i < 4; i++) {
            float4* o = (float4*)(pp + (g0 + i) * 64 + f0);
            o[0] = make_float4(acc[i][0], acc[i][1], acc[i][2], acc[i][3]);
            o[1] = make_float4(acc[i][4], acc[i][5], acc[i][6], acc[i][7]);
        }
    }
}

// ---------------------------------------------------------------------------
// K_B: slim reduce: 128 chunk-partials + ppart + bm0 + relu -> v0; BN0 stats.
// 256 blocks = 32 g-tiles x 8 f-grps; tiny LDS -> high occupancy.
// ---------------------------------------------------------------------------
__global__ __launch_bounds__(256) void k_reduce_bn0(
    const float* __restrict__ part, const float* __restrict__ ppart,
    const float* __restrict__ bm0, float* __restrict__ v0,
    float* __restrict__ stats0)
{
    __shared__ float r1[256];
    __shared__ float sv[64], sv2[64];
    const int bx = blockIdx.x, t = threadIdx.x;
    const int fgrp = bx & 7, gt = bx >> 3;
    const int fsub = t & 15, gl = (t >> 4) & 3, ch = t >> 6;
    const int f = fgrp * 16 + fsub, g = gt * 4 + gl;
    const int fh = f >> 6, fl = f & 63;

    const float* p = part + (size_t)(2 * (ch * 16) + fh) * 8192 + g * 64 + fl;
    float v = 0.f;
    #pragma unroll 4
    for (int cc = 0; cc < 16; cc++) v += p[(size_t)cc * 16384];

    r1[t] = v;
    __syncthreads();
    if (ch == 0) {
        v = r1[t] + r1[t + 64] + r1[t + 128] + r1[t + 192]
          + bm0[f] + ppart[g * DM + f];
        v = fmaxf(v, 0.f);
        v0[g * DM + f] = v;
        sv[t] = v; sv2[t] = v * v;
    }
    __syncthreads();
    if (t < 16) {
        float s1 = sv[t] + sv[t + 16] + sv[t + 32] + sv[t + 48];
        float s2 = sv2[t] + sv2[t + 16] + sv2[t + 32] + sv2[t + 48];
        atomicAdd(&stats0[(fgrp * 16 + t) * 2], s1);
        atomicAdd(&stats0[(fgrp * 16 + t) * 2 + 1], s2);
    }
}

// ---------------------------------------------------------------------------
// K5/K6: one MLP layer. 256 blocks = 128 f-cols x 2 graph-halves.
// BN of the PREVIOUS layer folded into the float4 staging load; stats atomics.
// ---------------------------------------------------------------------------
__global__ __launch_bounds__(256) void k_mlp(
    const float* __restrict__ vin, const float* __restrict__ statsin,
    const float* __restrict__ gbn, const float* __restrict__ bbn,
    const float* __restrict__ W, const float* __restrict__ bias,
    float* __restrict__ vout, float* __restrict__ statsout)
{
    __shared__ float scale_s[128], shift_s[128];
    __shared__ float wcol[128];
    __shared__ float pc[256];
    __shared__ float h_s[64 * 129];
    const int b = blockIdx.x, t = threadIdx.x;
    const int f = b & 127, gh = b >> 7;
    if (t < 128) {
        float s1 = statsin[t * 2], s2 = statsin[t * 2 + 1];
        float m = s1 * (1.f / 128.f);
        float var = s2 * (1.f / 128.f) - m * m;
        float sc = gbn[t] * rsqrtf(var + BN_EPS);
        scale_s[t] = sc;
        shift_s[t] = bbn[t] - m * sc;
        wcol[t] = W[t * 128 + f];
    }
    __syncthreads();
    const int g0r = gh * 64;
    const float4* vin4 = (const float4*)(vin + g0r * 128);
    #pragma unroll
    for (int it = 0; it < 8; ++it) {
        int idx = it * 256 + t;            // 2048 float4 = 64 rows x 128
        int gl = idx >> 5, k4 = (idx & 31) * 4;
        float4 vv = vin4[idx];
        float* hp = h_s + gl * 129 + k4;
        hp[0] = vv.x * scale_s[k4 + 0] + shift_s[k4 + 0];
        hp[1] = vv.y * scale_s[k4 + 1] + shift_s[k4 + 1];
        hp[2] = vv.z * scale_s[k4 + 2] + shift_s[k4 + 2];
        hp[3] = vv.w * scale_s[k4 + 3] + shift_s[k4 + 3];
    }
    __syncthreads();
    {
        const int gl = t & 63, kh = t >> 6;
        float acc = 0.f;
        #pragma unroll 8
        for (int k = kh * 32; k < kh * 32 + 32; ++k) acc += h_s[gl * 129 + k] * wcol[k];
        pc[gl * 4 + kh] = acc;
    }
    __syncthreads();
    if (t < 64) {   // wave 0
        float v = fmaxf(pc[t * 4] + pc[t * 4 + 1] + pc[t * 4 + 2] + pc[t * 4 + 3]
                        + bias[f], 0.f);
        vout[(size_t)(g0r + t) * 128 + f] = v;
        float s1 = v, s2 = v * v;
        #pragma unroll
        for (int off = 32; off > 0; off >>= 1) {
            s1 += __shfl_down(s1, off, 64);
            s2 += __shfl_down(s2, off, 64);
        }
        if (t == 0) {
            atomicAdd(&statsout[f * 2], s1);
            atomicAdd(&statsout[f * 2 + 1], s2);
        }
    }
}

// ---------------------------------------------------------------------------
// K7: output layer (BN2 folded at load). Block = 2 graph rows; coalesced out.
// ---------------------------------------------------------------------------
__global__ __launch_bounds__(128) void k_out(
    const float* __restrict__ vin, const float* __restrict__ statsin,
    const float* __restrict__ gbn, const float* __restrict__ bbn,
    const float* __restrict__ Wo, const float* __restrict__ bo,
    float* __restrict__ out)
{
    __shared__ __align__(16) float Wo_s[128 * 64];   // 32KB
    __shared__ float vrow[2][128];
    __shared__ float scale_s[128], shift_s[128];
    const int b = blockIdx.x, t = threadIdx.x, g0 = b * 2;
    {
        float s1 = statsin[t * 2], s2 = statsin[t * 2 + 1];
        float m = s1 * (1.f / 128.f);
        float var = s2 * (1.f / 128.f) - m * m;
        float sc = gbn[t] * rsqrtf(var + BN_EPS);
        scale_s[t] = sc;
        shift_s[t] = bbn[t] - m * sc;
    }
    __syncthreads();
    {
        const float4* wo4 = (const float4*)Wo;
        float4* wos4 = (float4*)Wo_s;
        #pragma unroll
        for (int it = 0; it < 16; it++) wos4[it * 128 + t] = wo4[it * 128 + t];
    }
    if (t < 64) {
        int g2 = t >> 5, k4 = (t & 31) * 4;
        float4 vv = ((const float4*)(vin + g0 * 128))[t];
        vrow[g2][k4 + 0] = vv.x * scale_s[k4 + 0] + shift_s[k4 + 0];
        vrow[g2][k4 + 1] = vv.y * scale_s[k4 + 1] + shift_s[k4 + 1];
        vrow[g2][k4 + 2] = vv.z * scale_s[k4 + 2] + shift_s[k4 + 2];
        vrow[g2][k4 + 3] = vv.w * scale_s[k4 + 3] + shift_s[k4 + 3];
    }
    __syncthreads();
    const int g2 = t >> 6, o = t & 63;
    float acc = bo[o];
    #pragma unroll 8
    for (int k = 0; k < 128; k++) acc += vrow[g2][k] * Wo_s[k * 64 + o];
    out[(g0 + g2) * NOUT + o] = acc;
}

extern "C" void kernel_launch(void* const* d_in, const int* in_sizes, int n_in,
                              void* d_out, int out_size, void* d_ws, size_t ws_size,
                              hipStream_t stream)
{
    const float* x   = (const float*)d_in[0];
    const float* ew  = (const float*)d_in[2];
    const float* W1  = (const float*)d_in[4];
    const float* b1  = (const float*)d_in[5];
    const float* W2  = (const float*)d_in[6];
    const float* b2  = (const float*)d_in[7];
    const float* Wm0 = (const float*)d_in[8];
    const float* bm0 = (const float*)d_in[9];
    const float* g0  = (const float*)d_in[10];
    const float* be0 = (const float*)d_in[11];
    const float* Wm1 = (const float*)d_in[12];
    const float* bm1 = (const float*)d_in[13];
    const float* g1  = (const float*)d_in[14];
    const float* be1 = (const float*)d_in[15];
    const float* Wm2 = (const float*)d_in[16];
    const float* bm2 = (const float*)d_in[17];
    const float* g2  = (const float*)d_in[18];
    const float* be2 = (const float*)d_in[19];
    const float* Wo  = (const float*)d_in[20];
    const float* bo  = (const float*)d_in[21];

    float* ws     = (float*)d_ws;
    float* part   = ws;                       // 128*8192 = 1048576
    float* ppartb = part + NCH * 8192;        // 16384
    float* v0     = ppartb + 16384;           // 16384
    float* v1     = v0 + 16384;               // 16384
    float* v2     = v1 + 16384;               // 16384
    float* stats  = v2 + 16384;               // 768 (stats0|stats1|stats2)

    k_front<<<256, 256, 0, stream>>>(x, ew, W1, b1, W2, b2, Wm0, part, ppartb, stats);
    k_reduce_bn0<<<256, 256, 0, stream>>>(part, ppartb, bm0, v0, stats);
    k_mlp<<<256, 256, 0, stream>>>(v0, stats,       g0, be0, Wm1, bm1, v1, stats + 256);
    k_mlp<<<256, 256, 0, stream>>>(v1, stats + 256, g1, be1, Wm2, bm2, v2, stats + 512);
    k_out<<<NOUT, 128, 0, stream>>>(v2, stats + 512, g2, be2, Wo, bo, (float*)d_out);
}

// Round 8
// 135.370 us; speedup vs baseline: 1.7384x; 1.0046x over previous
//
#include <hip/hip_runtime.h>

#define NG 128      // graphs
#define NPG 64      // nodes per graph
#define IN 16
#define DM 128      // d_model
#define NOUT 64
#define EPG 4096    // edges per graph (64x64)
#define NCH 128     // gemm chunks: 64 k-chunks(80) x 2 f-halves(64)
#define BN_EPS 1e-5f

// ---------------------------------------------------------------------------
// K_A "front": 256 blocks, one per CU.
//   blocks 0..127  = conv1 per graph -> pooled -> ppart (Wm0[0:128] product)
//   blocks 128..255 = big-GEMM x/ew chunks (80k x 64f) -> part
// dinv_i row-scaling folded into the P store (no ew-scale pass).
// ---------------------------------------------------------------------------
__global__ __launch_bounds__(256) void k_front(
    const float* __restrict__ x, const float* __restrict__ ew,
    const float* __restrict__ W1, const float* __restrict__ b1,
    const float* __restrict__ W2, const float* __restrict__ b2,
    const float* __restrict__ Wm0,
    float* __restrict__ part, float* __restrict__ ppart,
    float* __restrict__ stats)
{
    __shared__ __align__(16) float u[16128];   // 63KB union
    const int bid = blockIdx.x, t = threadIdx.x;

    if (bid < 128) {
        // ---------------- conv path (one block per graph) ----------------
        float* ew_s     = u;             // [i][j] 4096 (raw, never rescaled)
        float* x_s      = u + 4096;      // x^T [k][i] 1024
        float* W1_s     = u + 5120;      // [k][f] 2048
        float* P_s      = u + 7168;      // [i][f] 8192 (holds dinv_i * P)
        float* b1_s     = u + 15360;     // 128
        float* dinv_s   = u + 15488;     // 64
        float* t_s      = u + 15552;     // 64
        float* zp       = u + 4096;      // overlay (x_s/W1_s dead after P): 16*132
        float* z_full   = u + 15616;     // 128
        float* pooled_s = u + 15744;     // 128
        float* pp2      = u + 15872;     // 256
        const int g = bid;
        if (bid == 0) {
            for (int i = t; i < 768; i += 256) stats[i] = 0.f;
        }
        // stage: ew (vectorized), x transposed, W1 direct, b1
        {
            const float4* ew4 = (const float4*)(ew + g * EPG);
            float4* ews4 = (float4*)ew_s;
            #pragma unroll
            for (int i = 0; i < 4; i++) ews4[t + 256 * i] = ew4[t + 256 * i];
            const int xi = t & 63, k4 = (t >> 6) * 4;
            float4 xv = *(const float4*)(x + g * NPG * IN + xi * IN + k4);
            x_s[(k4 + 0) * 64 + xi] = xv.x;
            x_s[(k4 + 1) * 64 + xi] = xv.y;
            x_s[(k4 + 2) * 64 + xi] = xv.z;
            x_s[(k4 + 3) * 64 + xi] = xv.w;
            ((float4*)W1_s)[t]       = ((const float4*)W1)[t];
            ((float4*)W1_s)[t + 256] = ((const float4*)W1)[t + 256];
            if (t < 128) b1_s[t] = b1[t];
        }
        __syncthreads();

        // dinv: column sums of raw ew
        if (t < NPG) {
            float s = 0.f;
            #pragma unroll 8
            for (int i = 0; i < NPG; i++) s += ew_s[i * NPG + t];
            dinv_s[t] = (s > 0.f) ? rsqrtf(s) : 0.f;
        }
        __syncthreads();

        // t_s[i] = dinv_i * (sum_j ew[i,j] dinv_j) / 64
        {
            const int j = t & 63, q = t >> 6;
            const float dj = dinv_s[j];
            for (int i = q * 16; i < q * 16 + 16; i++) {
                float vv = ew_s[i * NPG + j] * dj;
                #pragma unroll
                for (int off = 32; off > 0; off >>= 1) vv += __shfl_down(vv, off, 64);
                if (j == 0) t_s[i] = dinv_s[i] * vv * (1.f / 64.f);
            }
        }

        // P' = dinv_i * (x @ W1) (64x128x16), register-blocked 4x8
        // (no barrier needed between t_s and P: disjoint LDS regions)
        {
            const int it = t & 15, ft = t >> 4;
            const int i0 = it * 4, f0 = ft * 8;
            float accp[4][8];
            #pragma unroll
            for (int a = 0; a < 4; a++)
                #pragma unroll
                for (int c = 0; c < 8; c++) accp[a][c] = 0.f;
            #pragma unroll
            for (int k = 0; k < IN; k++) {
                const float4 a4  = *(const float4*)(x_s + k * 64 + i0);
                const float4 b0v = *(const float4*)(W1_s + k * DM + f0);
                const float4 b1v = *(const float4*)(W1_s + k * DM + f0 + 4);
                const float av[4] = {a4.x, a4.y, a4.z, a4.w};
                const float bv[8] = {b0v.x, b0v.y, b0v.z, b0v.w, b1v.x, b1v.y, b1v.z, b1v.w};
                #pragma unroll
                for (int a = 0; a < 4; a++)
                    #pragma unroll
                    for (int c = 0; c < 8; c++) accp[a][c] += av[a] * bv[c];
            }
            #pragma unroll
            for (int a = 0; a < 4; a++) {
                const float di = dinv_s[i0 + a];
                float4* o = (float4*)(P_s + (i0 + a) * DM + f0);
                o[0] = make_float4(di * accp[a][0], di * accp[a][1],
                                   di * accp[a][2], di * accp[a][3]);
                o[1] = make_float4(di * accp[a][4], di * accp[a][5],
                                   di * accp[a][6], di * accp[a][7]);
            }
        }
        __syncthreads();

        // aggregation: h[j,f] = relu(dinv_j * sum_k ew[k,j] P'[k,f] + b1[f]);
        // z-partials per thread -> zp
        {
            const int jt = t & 15, ft = t >> 4;
            const int j0 = jt * 4, f0 = ft * 8;
            float acc[4][8];
            #pragma unroll
            for (int a = 0; a < 4; a++)
                #pragma unroll
                for (int c = 0; c < 8; c++) acc[a][c] = 0.f;
            #pragma unroll 4
            for (int k = 0; k < 64; k++) {
                const float4 a4  = *(const float4*)(ew_s + k * 64 + j0);
                const float4 b0v = *(const float4*)(P_s + k * DM + f0);
                const float4 b1v = *(const float4*)(P_s + k * DM + f0 + 4);
                const float av[4] = {a4.x, a4.y, a4.z, a4.w};
                const float bv[8] = {b0v.x, b0v.y, b0v.z, b0v.w, b1v.x, b1v.y, b1v.z, b1v.w};
                #pragma unroll
                for (int a = 0; a < 4; a++)
                    #pragma unroll
                    for (int c = 0; c < 8; c++) acc[a][c] += av[a] * bv[c];
            }
            float zpart[8];
            #pragma unroll
            for (int c = 0; c < 8; c++) zpart[c] = 0.f;
            #pragma unroll
            for (int a = 0; a < 4; a++) {
                const float dj = dinv_s[j0 + a], tj = t_s[j0 + a];
                #pragma unroll
                for (int c = 0; c < 8; c++) {
                    float h = fmaxf(dj * acc[a][c] + b1_s[f0 + c], 0.f);
                    zpart[c] += tj * h;
                }
            }
            float4* zo = (float4*)(zp + jt * 132 + f0);
            zo[0] = make_float4(zpart[0], zpart[1], zpart[2], zpart[3]);
            zo[1] = make_float4(zpart[4], zpart[5], zpart[6], zpart[7]);
        }
        __syncthreads();

        // z (LDS-resident only)
        if (t < 128) {
            float s = 0.f;
            #pragma unroll
            for (int jt = 0; jt < 16; jt++) s += zp[jt * 132 + t];
            z_full[t] = s;
        }
        __syncthreads();

        // pooled = relu(z @ W2 + b2): thread (c = t&127, kh = t>>7)
        {
            const int c = t & 127, kh = t >> 7;
            float acc = 0.f;
            #pragma unroll 8
            for (int k = kh * 64; k < kh * 64 + 64; k++)
                acc += z_full[k] * W2[k * DM + c];
            pp2[kh * 128 + c] = acc;
        }
        __syncthreads();
        if (t < 128) pooled_s[t] = fmaxf(pp2[t] + pp2[128 + t] + b2[t], 0.f);
        __syncthreads();

        // ppart = pooled @ Wm0[0:128,:]
        {
            const int f = t & 127, kh = t >> 7;
            float acc = 0.f;
            #pragma unroll 8
            for (int k = kh * 64; k < kh * 64 + 64; k++)
                acc += pooled_s[k] * Wm0[k * DM + f];
            pp2[kh * 128 + f] = acc;
        }
        __syncthreads();
        if (t < 128) ppart[g * DM + t] = pp2[t] + pp2[128 + t];
    } else {
        // ---------------- gemm x/ew chunk path (K=80) ----------------
        const int c = bid - 128;
        const int kc = c >> 1, fh = c & 1;
        const int K0 = kc * 80;          // feat col base in x|ew space (0..5120)
        float* a_s = u;                  // [k][g] 80*132 = 10560
        float* b_s = u + 10560;          // [k][fl] 80*64 = 5120

        #pragma unroll 4
        for (int it = 0; it < 32; it++) {
            int idx = it * 256 + t;
            int gg = idx >> 6, k = idx & 63;
            int K = K0 + k;
            float val = (K < 1024) ? x[gg * 1024 + K] : ew[gg * 4096 + (K - 1024)];
            a_s[k * 132 + gg] = fmaxf(val, 0.f);
        }
        #pragma unroll 4
        for (int it = 0; it < 8; it++) {
            int idx = it * 256 + t;
            int gg = idx >> 4, k = 64 + (idx & 15);
            int K = K0 + k;
            float val = (K < 1024) ? x[gg * 1024 + K] : ew[gg * 4096 + (K - 1024)];
            a_s[k * 132 + gg] = fmaxf(val, 0.f);
        }
        #pragma unroll 4
        for (int it = 0; it < 20; it++) {
            int idx = it * 256 + t;
            int k = idx >> 6, fl = idx & 63;
            b_s[k * 64 + fl] = Wm0[(128 + K0 + k) * 128 + fh * 64 + fl];
        }
        __syncthreads();

        const int gthr = t & 31, fthr = t >> 5;   // 32 x 8
        const int g0 = gthr * 4, f0 = fthr * 8;
        float acc[4][8];
        #pragma unroll
        for (int i = 0; i < 4; i++)
            #pragma unroll
            for (int jx = 0; jx < 8; jx++) acc[i][jx] = 0.f;

        #pragma unroll 4
        for (int k = 0; k < 80; k++) {
            const float4 a4  = *(const float4*)(a_s + k * 132 + g0);
            const float4 c0v = *(const float4*)(b_s + k * 64 + f0);
            const float4 c1v = *(const float4*)(b_s + k * 64 + f0 + 4);
            const float av[4] = {a4.x, a4.y, a4.z, a4.w};
            const float bv[8] = {c0v.x, c0v.y, c0v.z, c0v.w, c1v.x, c1v.y, c1v.z, c1v.w};
            #pragma unroll
            for (int i = 0; i < 4; i++)
                #pragma unroll
                for (int jx = 0; jx < 8; jx++) acc[i][jx] += av[i] * bv[jx];
        }

        float* pp = part + (size_t)c * 8192;    // [g][fl] 128x64
        #pragma unroll
        for (int i = 0; i < 4; i++) {
            float4* o = (float4*)(pp + (g0 + i) * 64 + f0);
            o[0] = make_float4(acc[i][0], acc[i][1], acc[i][2], acc[i][3]);
            o[1] = make_float4(acc[i][4], acc[i][5], acc[i][6], acc[i][7]);
        }
    }
}

// ---------------------------------------------------------------------------
// K_B: slim reduce (float4 loads): 128 chunk-partials + ppart + bm0 + relu
// -> v0; BN0 stats atomics. 256 blocks = 32 g-tiles x 8 f-grps.
// Thread: f4 = t&3 (4 cols), gl = (t>>2)&3 (graph), ch = t>>4 (16 chunk-grps).
// ---------------------------------------------------------------------------
__global__ __launch_bounds__(256) void k_reduce_bn0(
    const float* __restrict__ part, const float* __restrict__ ppart,
    const float* __restrict__ bm0, float* __restrict__ v0,
    float* __restrict__ stats0)
{
    __shared__ float r1[1024];    // [ch][gl][16f]
    __shared__ float sv[64], sv2[64];
    const int bx = blockIdx.x, t = threadIdx.x;
    const int fgrp = bx & 7, gt = bx >> 3;
    const int f4 = t & 3, gl = (t >> 2) & 3, ch = t >> 4;
    const int g = gt * 4 + gl;
    const int fbase = fgrp * 16 + f4 * 4;
    const int fh = fbase >> 6, fl = fbase & 63;

    // this thread: 4 k-chunks (of the 64 matching fh), float4 over f
    const float4* p = (const float4*)part
                    + ((size_t)(2 * (ch * 4) + fh) * 8192 + g * 64 + fl) / 4;
    float4 v = make_float4(0.f, 0.f, 0.f, 0.f);
    #pragma unroll
    for (int cc = 0; cc < 4; cc++) {
        float4 x4 = p[(size_t)cc * 4096];   // +2*8192 floats per k-chunk
        v.x += x4.x; v.y += x4.y; v.z += x4.z; v.w += x4.w;
    }
    float* r = r1 + ch * 64 + gl * 16 + f4 * 4;
    r[0] = v.x; r[1] = v.y; r[2] = v.z; r[3] = v.w;
    __syncthreads();

    if (t < 64) {
        const int fsub = t & 15, gl2 = t >> 4;
        const int f = fgrp * 16 + fsub, gg = gt * 4 + gl2;
        float s = bm0[f] + ppart[gg * DM + f];
        #pragma unroll
        for (int c2 = 0; c2 < 16; c2++) s += r1[c2 * 64 + gl2 * 16 + fsub];
        s = fmaxf(s, 0.f);
        v0[gg * DM + f] = s;
        sv[t] = s; sv2[t] = s * s;
    }
    __syncthreads();
    if (t < 16) {
        float s1 = sv[t] + sv[t + 16] + sv[t + 32] + sv[t + 48];
        float s2 = sv2[t] + sv2[t + 16] + sv2[t + 32] + sv2[t + 48];
        atomicAdd(&stats0[(fgrp * 16 + t) * 2], s1);
        atomicAdd(&stats0[(fgrp * 16 + t) * 2 + 1], s2);
    }
}

// ---------------------------------------------------------------------------
// K5/K6: one MLP layer. 256 blocks = 128 f-cols x 2 graph-halves. (unchanged)
// ---------------------------------------------------------------------------
__global__ __launch_bounds__(256) void k_mlp(
    const float* __restrict__ vin, const float* __restrict__ statsin,
    const float* __restrict__ gbn, const float* __restrict__ bbn,
    const float* __restrict__ W, const float* __restrict__ bias,
    float* __restrict__ vout, float* __restrict__ statsout)
{
    __shared__ float scale_s[128], shift_s[128];
    __shared__ float wcol[128];
    __shared__ float pc[256];
    __shared__ float h_s[64 * 129];
    const int b = blockIdx.x, t = threadIdx.x;
    const int f = b & 127, gh = b >> 7;
    if (t < 128) {
        float s1 = statsin[t * 2], s2 = statsin[t * 2 + 1];
        float m = s1 * (1.f / 128.f);
        float var = s2 * (1.f / 128.f) - m * m;
        float sc = gbn[t] * rsqrtf(var + BN_EPS);
        scale_s[t] = sc;
        shift_s[t] = bbn[t] - m * sc;
        wcol[t] = W[t * 128 + f];
    }
    __syncthreads();
    const int g0r = gh * 64;
    const float4* vin4 = (const float4*)(vin + g0r * 128);
    #pragma unroll
    for (int it = 0; it < 8; ++it) {
        int idx = it * 256 + t;            // 2048 float4 = 64 rows x 128
        int gl = idx >> 5, k4 = (idx & 31) * 4;
        float4 vv = vin4[idx];
        float* hp = h_s + gl * 129 + k4;
        hp[0] = vv.x * scale_s[k4 + 0] + shift_s[k4 + 0];
        hp[1] = vv.y * scale_s[k4 + 1] + shift_s[k4 + 1];
        hp[2] = vv.z * scale_s[k4 + 2] + shift_s[k4 + 2];
        hp[3] = vv.w * scale_s[k4 + 3] + shift_s[k4 + 3];
    }
    __syncthreads();
    {
        const int gl = t & 63, kh = t >> 6;
        float acc = 0.f;
        #pragma unroll 8
        for (int k = kh * 32; k < kh * 32 + 32; ++k) acc += h_s[gl * 129 + k] * wcol[k];
        pc[gl * 4 + kh] = acc;
    }
    __syncthreads();
    if (t < 64) {   // wave 0
        float v = fmaxf(pc[t * 4] + pc[t * 4 + 1] + pc[t * 4 + 2] + pc[t * 4 + 3]
                        + bias[f], 0.f);
        vout[(size_t)(g0r + t) * 128 + f] = v;
        float s1 = v, s2 = v * v;
        #pragma unroll
        for (int off = 32; off > 0; off >>= 1) {
            s1 += __shfl_down(s1, off, 64);
            s2 += __shfl_down(s2, off, 64);
        }
        if (t == 0) {
            atomicAdd(&statsout[f * 2], s1);
            atomicAdd(&statsout[f * 2 + 1], s2);
        }
    }
}

// ---------------------------------------------------------------------------
// K7: output layer (BN2 folded at load). Block = 2 graph rows. (unchanged)
// ---------------------------------------------------------------------------
__global__ __launch_bounds__(128) void k_out(
    const float* __restrict__ vin, const float* __restrict__ statsin,
    const float* __restrict__ gbn, const float* __restrict__ bbn,
    const float* __restrict__ Wo, const float* __restrict__ bo,
    float* __restrict__ out)
{
    __shared__ __align__(16) float Wo_s[128 * 64];   // 32KB
    __shared__ float vrow[2][128];
    __shared__ float scale_s[128], shift_s[128];
    const int b = blockIdx.x, t = threadIdx.x, g0 = b * 2;
    {
        float s1 = statsin[t * 2], s2 = statsin[t * 2 + 1];
        float m = s1 * (1.f / 128.f);
        float var = s2 * (1.f / 128.f) - m * m;
        float sc = gbn[t] * rsqrtf(var + BN_EPS);
        scale_s[t] = sc;
        shift_s[t] = bbn[t] - m * sc;
    }
    __syncthreads();
    {
        const float4* wo4 = (const float4*)Wo;
        float4* wos4 = (float4*)Wo_s;
        #pragma unroll
        for (int it = 0; it < 16; it++) wos4[it * 128 + t] = wo4[it * 128 + t];
    }
    if (t < 64) {
        int g2 = t >> 5, k4 = (t & 31) * 4;
        float4 vv = ((const float4*)(vin + g0 * 128))[t];
        vrow[g2][k4 + 0] = vv.x * scale_s[k4 + 0] + shift_s[k4 + 0];
        vrow[g2][k4 + 1] = vv.y * scale_s[k4 + 1] + shift_s[k4 + 1];
        vrow[g2][k4 + 2] = vv.z * scale_s[k4 + 2] + shift_s[k4 + 2];
        vrow[g2][k4 + 3] = vv.w * scale_s[k4 + 3] + shift_s[k4 + 3];
    }
    __syncthreads();
    const int g2 = t >> 6, o = t & 63;
    float acc = bo[o];
    #pragma unroll 8
    for (int k = 0; k < 128; k++) acc += vrow[g2][k] * Wo_s[k * 64 + o];
    out[(g0 + g2) * NOUT + o] = acc;
}

extern "C" void kernel_launch(void* const* d_in, const int* in_sizes, int n_in,
                              void* d_out, int out_size, void* d_ws, size_t ws_size,
                              hipStream_t stream)
{
    const float* x   = (const float*)d_in[0];
    const float* ew  = (const float*)d_in[2];
    const float* W1  = (const float*)d_in[4];
    const float* b1  = (const float*)d_in[5];
    const float* W2  = (const float*)d_in[6];
    const float* b2  = (const float*)d_in[7];
    const float* Wm0 = (const float*)d_in[8];
    const float* bm0 = (const float*)d_in[9];
    const float* g0  = (const float*)d_in[10];
    const float* be0 = (const float*)d_in[11];
    const float* Wm1 = (const float*)d_in[12];
    const float* bm1 = (const float*)d_in[13];
    const float* g1  = (const float*)d_in[14];
    const float* be1 = (const float*)d_in[15];
    const float* Wm2 = (const float*)d_in[16];
    const float* bm2 = (const float*)d_in[17];
    const float* g2  = (const float*)d_in[18];
    const float* be2 = (const float*)d_in[19];
    const float* Wo  = (const float*)d_in[20];
    const float* bo  = (const float*)d_in[21];

    float* ws     = (float*)d_ws;
    float* part   = ws;                       // 128*8192 = 1048576
    float* ppartb = part + NCH * 8192;        // 16384
    float* v0     = ppartb + 16384;           // 16384
    float* v1     = v0 + 16384;               // 16384
    float* v2     = v1 + 16384;               // 16384
    float* stats  = v2 + 16384;               // 768 (stats0|stats1|stats2)

    k_front<<<256, 256, 0, stream>>>(x, ew, W1, b1, W2, b2, Wm0, part, ppartb, stats);
    k_reduce_bn0<<<256, 256, 0, stream>>>(part, ppartb, bm0, v0, stats);
    k_mlp<<<256, 256, 0, stream>>>(v0, stats,       g0, be0, Wm1, bm1, v1, stats + 256);
    k_mlp<<<256, 256, 0, stream>>>(v1, stats + 256, g1, be1, Wm2, bm2, v2, stats + 512);
    k_out<<<NOUT, 128, 0, stream>>>(v2, stats + 512, g2, be2, Wo, bo, (float*)d_out);
}